// Round 2
// 1096.852 us; speedup vs baseline: 1.0185x; 1.0185x over previous
//
#include <hip/hip_runtime.h>
#include <hip/hip_bf16.h>

typedef __hip_bfloat16 bf16;
typedef __attribute__((ext_vector_type(8))) short short8;
typedef __attribute__((ext_vector_type(4))) float floatx4;

__device__ __forceinline__ floatx4 mfma16(short8 a, short8 b, floatx4 c) {
  return __builtin_amdgcn_mfma_f32_16x16x32_bf16(a, b, c, 0, 0, 0);
}

__device__ __forceinline__ float wave_sum(float v) {
#pragma unroll
  for (int off = 1; off < 64; off <<= 1) v += __shfl_xor(v, off);
  return v;
}

// async global -> LDS, 16 bytes per lane
__device__ __forceinline__ void gload16(const void* g, void* l) {
  __builtin_amdgcn_global_load_lds(
      (const __attribute__((address_space(1))) unsigned int*)g,
      (__attribute__((address_space(3))) unsigned int*)l, 16, 0, 0);
}

// swizzled LDS fragment read: row stride 384B, XOR bits[6:4] with row&7
__device__ __forceinline__ short8 lds_frag(const char* base, int row, int kb) {
  return *(const short8*)(base + row * 384 + (kb ^ ((row & 7) << 4)));
}

// ---------------------------------------------------------------------------
// Weight transpose + bf16 cast: w (K x N) fp32 -> wt (N x K) bf16
// ---------------------------------------------------------------------------
__global__ __launch_bounds__(256) void k_wt(const float* __restrict__ w,
                                            bf16* __restrict__ wt, int K, int N) {
  int id = blockIdx.x * 256 + threadIdx.x;
  if (id < K * N) {
    int n = id / K;
    int k = id - n * K;
    wt[id] = __float2bfloat16(w[(long)k * N + n]);
  }
}

// ---------------------------------------------------------------------------
// LayerNorm over C=192. One wave per row. GATHER=true applies cyclic shift
// (-3,-3) + window partition: output row order = (b, wi, wj, ti, tj).
// ---------------------------------------------------------------------------
template <bool GATHER>
__global__ __launch_bounds__(256) void k_ln(const float* __restrict__ xin,
                                            const float* __restrict__ w,
                                            const float* __restrict__ b,
                                            bf16* __restrict__ out) {
  const int lane = threadIdx.x & 63;
  const long row = (long)blockIdx.x * 4 + (threadIdx.x >> 6);
  long srow;
  if (GATHER) {
    int win = (int)(row / 49);
    int token = (int)(row - (long)win * 49);
    int bimg = win >> 6, wi = (win & 63) >> 3, wj = win & 7;
    int ti = token / 7, tj = token - ti * 7;
    int h = wi * 7 + ti + 3; if (h >= 56) h -= 56;
    int ww = wj * 7 + tj + 3; if (ww >= 56) ww -= 56;
    srow = (long)bimg * 3136 + h * 56 + ww;
  } else {
    srow = row;
  }
  const float* src = xin + srow * 192;
  float v0 = src[lane], v1 = src[lane + 64], v2 = src[lane + 128];
  float mu = wave_sum(v0 + v1 + v2) * (1.f / 192.f);
  float d0 = v0 - mu, d1 = v1 - mu, d2 = v2 - mu;
  float var = wave_sum(d0 * d0 + d1 * d1 + d2 * d2) * (1.f / 192.f);
  float rs = rsqrtf(var + 1e-5f);
  bf16* dst = out + row * 192;
  dst[lane]       = __float2bfloat16(d0 * rs * w[lane] + b[lane]);
  dst[lane + 64]  = __float2bfloat16(d1 * rs * w[lane + 64] + b[lane + 64]);
  dst[lane + 128] = __float2bfloat16(d2 * rs * w[lane + 128] + b[lane + 128]);
}

// ---------------------------------------------------------------------------
// GEMM: C = A (M x K, bf16 rm) * Bt^T (Bt is N x K bf16) + bias
// 64x64 block tile, 4 waves of 32x32, MFMA 16x16x32 bf16.
// Full 192-wide K panels staged to LDS via global_load_lds (linear dest),
// XOR-swizzled source bytes + matching swizzled ds_read (2-way, free).
// Per panel: 2 barriers, 24 MFMA/wave back-to-back.
// EPI 0: store bf16 (ldc = Ncols)                      [qkv]
// EPI 1: exact GELU, store bf16                        [fc1]
// EPI 2: window-reverse scatter + shortcut add, fp32   [proj -> d_out]
// EPI 3: + res[row], fp32 (res/Cfp pre-offset)         [fc2 -> d_out]
// ---------------------------------------------------------------------------
template <int EPI>
__global__ __launch_bounds__(256, 3) void k_gemm(const bf16* __restrict__ A,
                                                 const bf16* __restrict__ Bt,
                                                 const float* __restrict__ bias,
                                                 bf16* __restrict__ Cbf,
                                                 float* __restrict__ Cfp,
                                                 const float* __restrict__ res,
                                                 int Ncols, int K, long row0) {
  __shared__ __align__(16) char As[64 * 384];  // 24576 B: 64 rows x 192 bf16
  __shared__ __align__(16) char Bs[64 * 384];
  const int t = threadIdx.x;
  const int lane = t & 63, wid = t >> 6;
  const int lanelo = lane & 15, quad = lane >> 4;
  const long m0 = (long)blockIdx.x * 64;
  const int n0 = blockIdx.y * 64;
  const int wm = (wid >> 1) * 32, wn = (wid & 1) * 32;

  floatx4 acc[2][2];
#pragma unroll
  for (int i = 0; i < 2; i++)
#pragma unroll
    for (int j = 0; j < 2; j++) acc[i][j] = (floatx4){0.f, 0.f, 0.f, 0.f};

  const char* Ab = (const char*)(A + m0 * (long)K);
  const char* Bb = (const char*)(Bt + (long)n0 * K);
  const int ldab = 2 * K;  // bytes per source row

  for (int k0b = 0; k0b < 2 * K; k0b += 384) {
    __syncthreads();
    // stage one 64x192 panel of A and of B: 1536 16B-chunks each, 6/thread.
    // LDS dest is linear (chunk c at byte c*16); global source byte-in-row is
    // XOR-swizzled so that the ds_read side can unswizzle conflict-free.
#pragma unroll
    for (int i = 0; i < 6; i++) {
      int c = i * 256 + t;          // chunk index
      int r = c / 24;               // row in tile (24 chunks per 384B row)
      int j = c - r * 24;
      int be = (j * 16) ^ ((r & 7) << 4);
      gload16(Ab + (long)r * ldab + k0b + be, As + c * 16);
      gload16(Bb + (long)r * ldab + k0b + be, Bs + c * 16);
    }
    __syncthreads();  // drains vmcnt(0) -> panels resident

#pragma unroll
    for (int kk = 0; kk < 6; kk++) {
      const int kb = kk * 64 + quad * 16;  // byte offset of this lane's k-slice
      short8 a0 = lds_frag(As, wm + lanelo, kb);
      short8 a1 = lds_frag(As, wm + 16 + lanelo, kb);
      short8 b0 = lds_frag(Bs, wn + lanelo, kb);
      short8 b1 = lds_frag(Bs, wn + 16 + lanelo, kb);
      acc[0][0] = mfma16(a0, b0, acc[0][0]);
      acc[0][1] = mfma16(a0, b1, acc[0][1]);
      acc[1][0] = mfma16(a1, b0, acc[1][0]);
      acc[1][1] = mfma16(a1, b1, acc[1][1]);
    }
  }

#pragma unroll
  for (int mi = 0; mi < 2; mi++) {
#pragma unroll
    for (int reg = 0; reg < 4; reg++) {
      const long r = m0 + wm + mi * 16 + quad * 4 + reg;
      long orow = r;
      if (EPI == 2) {
        const long rg = row0 + r;
        int win = (int)(rg / 49);
        int token = (int)(rg - (long)win * 49);
        int bimg = win >> 6, wi = (win & 63) >> 3, wj = win & 7;
        int ti = token / 7, tj = token - ti * 7;
        int h = wi * 7 + ti + 3; if (h >= 56) h -= 56;
        int ww = wj * 7 + tj + 3; if (ww >= 56) ww -= 56;
        orow = (long)bimg * 3136 + h * 56 + ww;
      }
#pragma unroll
      for (int ni = 0; ni < 2; ni++) {
        const int c = n0 + wn + ni * 16 + lanelo;
        float v = acc[mi][ni][reg] + bias[c];
        if (EPI == 0) {
          Cbf[r * Ncols + c] = __float2bfloat16(v);
        } else if (EPI == 1) {
          v = 0.5f * v * (1.f + erff(v * 0.70710678118654752f));
          Cbf[r * Ncols + c] = __float2bfloat16(v);
        } else if (EPI == 2) {
          Cfp[orow * 192 + c] = v + res[orow * 192 + c];
        } else {
          Cfp[r * 192 + c] = v + res[r * 192 + c];
        }
      }
    }
  }
}

// ---------------------------------------------------------------------------
// Windowed attention over a CHUNK of windows. One wave per (window, head).
// N=49 padded to 64. qkv rows are chunk-local; `out` is pre-offset.
// Spatial labels use win & 63 (valid: chunks are whole images).
// ---------------------------------------------------------------------------
__global__ __launch_bounds__(256, 2) void k_attn(const bf16* __restrict__ qkv,
                                                 const float* __restrict__ rpb,
                                                 bf16* __restrict__ out) {
  __shared__ __align__(16) bf16 smem[4 * 7424];
  const int t = threadIdx.x, lane = t & 63, wid = t >> 6;
  const int lanelo = lane & 15, quad = lane >> 4;
  const int unit = blockIdx.x * 4 + wid;
  const int win = unit / 6, head = unit - win * 6;
  bf16* Qs = smem + wid * 7424;  // 64 rows, stride 40
  bf16* Ks = Qs + 2560;          // 64 rows, stride 40
  bf16* Vt = Qs + 5120;          // 32 rows (d), stride 72, cols = token
  bf16* Ps = Qs;                 // 64 rows, stride 72 (4608 <= 5120, reuse Q/K)
  const long rowbase = (long)win * 49;
  const bf16* base = qkv + rowbase * 576 + head * 32;

  // stage Q, K (row-major) and V transposed; 49 rows x 32 cols each
  for (int idx = lane; idx < 196; idx += 64) {
    int tok = idx >> 2, ch = (idx & 3) * 8;
    *(uint4*)(&Qs[tok * 40 + ch]) = *(const uint4*)(base + (long)tok * 576 + ch);
    *(uint4*)(&Ks[tok * 40 + ch]) = *(const uint4*)(base + (long)tok * 576 + 192 + ch);
    union { uint4 u; bf16 h[8]; } tv;
    tv.u = *(const uint4*)(base + (long)tok * 576 + 384 + ch);
#pragma unroll
    for (int jj = 0; jj < 8; jj++) Vt[(ch + jj) * 72 + tok] = tv.h[jj];
  }
  // zero V pad tokens 49..63 (keep P*V clean in pad region)
  for (int idx = lane; idx < 480; idx += 64) {
    int d = idx / 15, c = 49 + (idx - d * 15);
    Vt[d * 72 + c] = __float2bfloat16(0.f);
  }
  __syncthreads();

  // S = Q * K^T : 64x64 via 4x4 fragments, single K-step (HD=32)
  floatx4 aS[4][4];
#pragma unroll
  for (int mi = 0; mi < 4; mi++)
#pragma unroll
    for (int ni = 0; ni < 4; ni++) aS[mi][ni] = (floatx4){0.f, 0.f, 0.f, 0.f};
  {
    short8 aq[4], bk[4];
#pragma unroll
    for (int mi = 0; mi < 4; mi++)
      aq[mi] = *(const short8*)(&Qs[(mi * 16 + lanelo) * 40 + quad * 8]);
#pragma unroll
    for (int ni = 0; ni < 4; ni++)
      bk[ni] = *(const short8*)(&Ks[(ni * 16 + lanelo) * 40 + quad * 8]);
#pragma unroll
    for (int mi = 0; mi < 4; mi++)
#pragma unroll
      for (int ni = 0; ni < 4; ni++) aS[mi][ni] = mfma16(aq[mi], bk[ni], aS[mi][ni]);
  }

  // per-column (key j) tables for this lane
  const int w_in = win & 63, wiw = w_in >> 3, wjw = w_in & 7;
  int cTi[4], cTj[4], cLab[4];
  bool cval[4];
#pragma unroll
  for (int ni = 0; ni < 4; ni++) {
    int j = ni * 16 + lanelo;
    cval[ni] = (j < 49);
    if (j > 48) j = 48;
    int ti = j / 7, tj = j - ti * 7;
    int rr = wiw * 7 + ti, cc = wjw * 7 + tj;
    cTi[ni] = ti;
    cTj[ni] = tj;
    cLab[ni] = ((rr < 49) ? 0 : (rr < 53 ? 1 : 2)) * 3 +
               ((cc < 49) ? 0 : (cc < 53 ? 1 : 2));
  }

  const float scale = 0.17677669529663687f;  // 1/sqrt(32)
  float rinv[16];
#pragma unroll
  for (int mi = 0; mi < 4; mi++) {
#pragma unroll
    for (int reg = 0; reg < 4; reg++) {
      int i = mi * 16 + quad * 4 + reg;
      if (i > 48) i = 48;
      int ti = i / 7, tj = i - ti * 7;
      int rr = wiw * 7 + ti, cc = wjw * 7 + tj;
      int rlab = ((rr < 49) ? 0 : (rr < 53 ? 1 : 2)) * 3 +
                 ((cc < 49) ? 0 : (cc < 53 ? 1 : 2));
      float sv[4];
      float mx = -1e30f;
#pragma unroll
      for (int ni = 0; ni < 4; ni++) {
        float s;
        if (cval[ni]) {
          int ridx = (ti - cTi[ni] + 6) * 13 + (tj - cTj[ni] + 6);
          float bb = rpb[ridx * 6 + head];
          if (rlab != cLab[ni]) bb -= 100.f;
          s = aS[mi][ni][reg] * scale + bb;
        } else {
          s = -1e30f;
        }
        sv[ni] = s;
        mx = fmaxf(mx, s);
      }
      mx = fmaxf(mx, __shfl_xor(mx, 1));
      mx = fmaxf(mx, __shfl_xor(mx, 2));
      mx = fmaxf(mx, __shfl_xor(mx, 4));
      mx = fmaxf(mx, __shfl_xor(mx, 8));
      float sum = 0.f;
#pragma unroll
      for (int ni = 0; ni < 4; ni++) {
        float p = __expf(sv[ni] - mx);
        sv[ni] = p;
        sum += p;
      }
      sum += __shfl_xor(sum, 1);
      sum += __shfl_xor(sum, 2);
      sum += __shfl_xor(sum, 4);
      sum += __shfl_xor(sum, 8);
      rinv[mi * 4 + reg] = 1.f / sum;
#pragma unroll
      for (int ni = 0; ni < 4; ni++) aS[mi][ni][reg] = sv[ni];
    }
  }
  __syncthreads();

  // P -> LDS in A-operand layout (row i, contiguous j)
#pragma unroll
  for (int mi = 0; mi < 4; mi++)
#pragma unroll
    for (int ni = 0; ni < 4; ni++)
#pragma unroll
      for (int reg = 0; reg < 4; reg++) {
        int i = mi * 16 + quad * 4 + reg, j = ni * 16 + lanelo;
        Ps[i * 72 + j] = __float2bfloat16(aS[mi][ni][reg]);
      }
  __syncthreads();

  // O = P * V : 64x32, K=64 in 2 steps
  floatx4 aO[4][2];
#pragma unroll
  for (int mi = 0; mi < 4; mi++)
#pragma unroll
    for (int ni = 0; ni < 2; ni++) aO[mi][ni] = (floatx4){0.f, 0.f, 0.f, 0.f};
#pragma unroll
  for (int k0 = 0; k0 < 64; k0 += 32) {
    short8 ap[4], bv[2];
#pragma unroll
    for (int mi = 0; mi < 4; mi++)
      ap[mi] = *(const short8*)(&Ps[(mi * 16 + lanelo) * 72 + k0 + quad * 8]);
#pragma unroll
    for (int ni = 0; ni < 2; ni++)
      bv[ni] = *(const short8*)(&Vt[(ni * 16 + lanelo) * 72 + k0 + quad * 8]);
#pragma unroll
    for (int mi = 0; mi < 4; mi++)
#pragma unroll
      for (int ni = 0; ni < 2; ni++) aO[mi][ni] = mfma16(ap[mi], bv[ni], aO[mi][ni]);
  }

#pragma unroll
  for (int mi = 0; mi < 4; mi++)
#pragma unroll
    for (int reg = 0; reg < 4; reg++) {
      int i = mi * 16 + quad * 4 + reg;
      if (i < 49) {
        float rv = rinv[mi * 4 + reg];
#pragma unroll
        for (int ni = 0; ni < 2; ni++) {
          int d = ni * 16 + lanelo;
          out[(rowbase + i) * 192 + head * 32 + d] =
              __float2bfloat16(aO[mi][ni][reg] * rv);
        }
      }
    }
}

// ---------------------------------------------------------------------------
extern "C" void kernel_launch(void* const* d_in, const int* in_sizes, int n_in,
                              void* d_out, int out_size, void* d_ws, size_t ws_size,
                              hipStream_t stream) {
  const float* x     = (const float*)d_in[0];
  const float* n1w   = (const float*)d_in[1];
  const float* n1b   = (const float*)d_in[2];
  const float* qkvw  = (const float*)d_in[3];
  const float* qkvb  = (const float*)d_in[4];
  const float* rpb   = (const float*)d_in[5];
  const float* projw = (const float*)d_in[6];
  const float* projb = (const float*)d_in[7];
  const float* n2w   = (const float*)d_in[8];
  const float* n2b   = (const float*)d_in[9];
  const float* fc1w  = (const float*)d_in[10];
  const float* fc1b  = (const float*)d_in[11];
  const float* fc2w  = (const float*)d_in[12];
  const float* fc2b  = (const float*)d_in[13];
  float* outf = (float*)d_out;  // doubles as the residual buffer x2

  // Chunking: 4 chunks x 1024 windows (= 16 images) = 50176 rows each.
  const long CR = 50176;     // rows per chunk
  const int  NCH = 4;

  // workspace layout (total ~155 MB):
  //   B0 [0,        77070336)  xw bf16 (200704x192); later m (LN2 out)
  //   B1 [77070336, 134873088) qkv chunk bf16 (50176x576)
  //   B2 [134873088,154140672) attn chunk bf16 (50176x192)
  //   B1' [77070336,154140672) hidden chunk bf16 (50176x768)  [MLP phase]
  //   W  [154140672, ...)      bf16 weights (~0.9 MB)
  char* ws = (char*)d_ws;
  bf16* xw      = (bf16*)(ws + 0);
  bf16* qkvC    = (bf16*)(ws + 77070336LL);
  bf16* attC    = (bf16*)(ws + 134873088LL);
  bf16* hidC    = (bf16*)(ws + 77070336LL);
  bf16* m       = xw;
  bf16* wt_qkv  = (bf16*)(ws + 154140672LL);                  // 576x192
  bf16* wt_proj = (bf16*)(ws + 154140672LL + 221184LL);       // 192x192
  bf16* wt_fc1  = (bf16*)(ws + 154140672LL + 294912LL);       // 768x192
  bf16* wt_fc2  = (bf16*)(ws + 154140672LL + 589824LL);       // 192x768
  // total: 154140672 + 884736 = 155,025,408 bytes

  // transpose + cast weights to bf16 (N x K)
  k_wt<<<dim3((192 * 576 + 255) / 256), 256, 0, stream>>>(qkvw, wt_qkv, 192, 576);
  k_wt<<<dim3((192 * 192 + 255) / 256), 256, 0, stream>>>(projw, wt_proj, 192, 192);
  k_wt<<<dim3((192 * 768 + 255) / 256), 256, 0, stream>>>(fc1w, wt_fc1, 192, 768);
  k_wt<<<dim3((768 * 192 + 255) / 256), 256, 0, stream>>>(fc2w, wt_fc2, 768, 192);

  // LN1 + shift + window partition -> xw (window-order rows, full tensor)
  k_ln<true><<<dim3(50176), 256, 0, stream>>>(x, n1w, n1b, xw);

  // attention phase, chunked
  for (int c = 0; c < NCH; c++) {
    const long r0 = c * CR;
    k_gemm<0><<<dim3(784, 9), 256, 0, stream>>>(xw + r0 * 192, wt_qkv, qkvb,
                                                qkvC, nullptr, nullptr, 576, 192, 0);
    k_attn<<<dim3(1536), 256, 0, stream>>>(qkvC, rpb, attC);
    k_gemm<2><<<dim3(784, 3), 256, 0, stream>>>(attC, wt_proj, projb, nullptr,
                                                outf, x, 192, 192, r0);
  }

  // LN2 -> m (reuses xw region)
  k_ln<false><<<dim3(50176), 256, 0, stream>>>(outf, n2w, n2b, m);

  // MLP phase, chunked; fc2 adds the residual in-place into d_out
  for (int c = 0; c < NCH; c++) {
    const long r0 = c * CR;
    k_gemm<1><<<dim3(784, 12), 256, 0, stream>>>(m + r0 * 192, wt_fc1, fc1b,
                                                 hidC, nullptr, nullptr, 768, 192, 0);
    k_gemm<3><<<dim3(784, 3), 256, 0, stream>>>(hidC, wt_fc2, fc2b, nullptr,
                                                outf + r0 * 192, outf + r0 * 192,
                                                192, 768, 0);
  }
}

// Round 3
// 1014.987 us; speedup vs baseline: 1.1007x; 1.0807x over previous
//
#include <hip/hip_runtime.h>
#include <hip/hip_bf16.h>

typedef __hip_bfloat16 bf16;
typedef __attribute__((ext_vector_type(8))) short short8;
typedef __attribute__((ext_vector_type(4))) float floatx4;

__device__ __forceinline__ floatx4 mfma16(short8 a, short8 b, floatx4 c) {
  return __builtin_amdgcn_mfma_f32_16x16x32_bf16(a, b, c, 0, 0, 0);
}

__device__ __forceinline__ float wave_sum(float v) {
#pragma unroll
  for (int off = 1; off < 64; off <<= 1) v += __shfl_xor(v, off);
  return v;
}

// async global -> LDS, 16 bytes per lane
__device__ __forceinline__ void gload16(const void* g, void* l) {
  __builtin_amdgcn_global_load_lds(
      (const __attribute__((address_space(1))) unsigned int*)g,
      (__attribute__((address_space(3))) unsigned int*)l, 16, 0, 0);
}

// swizzled LDS fragment read: row stride 384B, XOR bits[6:4] with row&7
__device__ __forceinline__ short8 lds_frag(const char* base, int row, int kb) {
  return *(const short8*)(base + row * 384 + (kb ^ ((row & 7) << 4)));
}
// same, row stride 128B
__device__ __forceinline__ short8 lds_frag128(const char* base, int row, int kb) {
  return *(const short8*)(base + row * 128 + (kb ^ ((row & 7) << 4)));
}

// ---------------------------------------------------------------------------
// Weight transpose + bf16 cast: w (K x N) fp32 -> wt (N x K) bf16
// ---------------------------------------------------------------------------
__global__ __launch_bounds__(256) void k_wt(const float* __restrict__ w,
                                            bf16* __restrict__ wt, int K, int N) {
  int id = blockIdx.x * 256 + threadIdx.x;
  if (id < K * N) {
    int n = id / K;
    int k = id - n * K;
    wt[id] = __float2bfloat16(w[(long)k * N + n]);
  }
}

// ---------------------------------------------------------------------------
// LayerNorm over C=192. One wave per row. GATHER=true applies cyclic shift
// (-3,-3) + window partition: output row order = (b, wi, wj, ti, tj).
// ---------------------------------------------------------------------------
template <bool GATHER>
__global__ __launch_bounds__(256) void k_ln(const float* __restrict__ xin,
                                            const float* __restrict__ w,
                                            const float* __restrict__ b,
                                            bf16* __restrict__ out) {
  const int lane = threadIdx.x & 63;
  const long row = (long)blockIdx.x * 4 + (threadIdx.x >> 6);
  long srow;
  if (GATHER) {
    int win = (int)(row / 49);
    int token = (int)(row - (long)win * 49);
    int bimg = win >> 6, wi = (win & 63) >> 3, wj = win & 7;
    int ti = token / 7, tj = token - ti * 7;
    int h = wi * 7 + ti + 3; if (h >= 56) h -= 56;
    int ww = wj * 7 + tj + 3; if (ww >= 56) ww -= 56;
    srow = (long)bimg * 3136 + h * 56 + ww;
  } else {
    srow = row;
  }
  const float* src = xin + srow * 192;
  float v0 = src[lane], v1 = src[lane + 64], v2 = src[lane + 128];
  float mu = wave_sum(v0 + v1 + v2) * (1.f / 192.f);
  float d0 = v0 - mu, d1 = v1 - mu, d2 = v2 - mu;
  float var = wave_sum(d0 * d0 + d1 * d1 + d2 * d2) * (1.f / 192.f);
  float rs = rsqrtf(var + 1e-5f);
  bf16* dst = out + row * 192;
  dst[lane]       = __float2bfloat16(d0 * rs * w[lane] + b[lane]);
  dst[lane + 64]  = __float2bfloat16(d1 * rs * w[lane + 64] + b[lane + 64]);
  dst[lane + 128] = __float2bfloat16(d2 * rs * w[lane + 128] + b[lane + 128]);
}

// ---------------------------------------------------------------------------
// GEMM: C = A (M x K, bf16 rm) * Bt^T (Bt is N x K bf16) + bias
// 64x64 block tile, 4 waves of 32x32, MFMA 16x16x32 bf16.
// Full 192-wide K panels staged to LDS via global_load_lds (linear dest),
// XOR-swizzled source bytes + matching swizzled ds_read.
// EPI 0: store bf16 (ldc = Ncols)                      [qkv]
// EPI 2: window-reverse scatter + shortcut add, fp32   [proj -> d_out]
// ---------------------------------------------------------------------------
template <int EPI>
__global__ __launch_bounds__(256, 3) void k_gemm(const bf16* __restrict__ A,
                                                 const bf16* __restrict__ Bt,
                                                 const float* __restrict__ bias,
                                                 bf16* __restrict__ Cbf,
                                                 float* __restrict__ Cfp,
                                                 const float* __restrict__ res,
                                                 int Ncols, int K, long row0) {
  __shared__ __align__(16) char As[64 * 384];  // 24576 B: 64 rows x 192 bf16
  __shared__ __align__(16) char Bs[64 * 384];
  const int t = threadIdx.x;
  const int lane = t & 63, wid = t >> 6;
  const int lanelo = lane & 15, quad = lane >> 4;
  const long m0 = (long)blockIdx.x * 64;
  const int n0 = blockIdx.y * 64;
  const int wm = (wid >> 1) * 32, wn = (wid & 1) * 32;

  floatx4 acc[2][2];
#pragma unroll
  for (int i = 0; i < 2; i++)
#pragma unroll
    for (int j = 0; j < 2; j++) acc[i][j] = (floatx4){0.f, 0.f, 0.f, 0.f};

  const char* Ab = (const char*)(A + m0 * (long)K);
  const char* Bb = (const char*)(Bt + (long)n0 * K);
  const int ldab = 2 * K;  // bytes per source row

  for (int k0b = 0; k0b < 2 * K; k0b += 384) {
    __syncthreads();
#pragma unroll
    for (int i = 0; i < 6; i++) {
      int c = i * 256 + t;          // chunk index
      int r = c / 24;               // row in tile (24 chunks per 384B row)
      int j = c - r * 24;
      int be = (j * 16) ^ ((r & 7) << 4);
      gload16(Ab + (long)r * ldab + k0b + be, As + c * 16);
      gload16(Bb + (long)r * ldab + k0b + be, Bs + c * 16);
    }
    __syncthreads();  // drains vmcnt(0) -> panels resident

#pragma unroll
    for (int kk = 0; kk < 6; kk++) {
      const int kb = kk * 64 + quad * 16;
      short8 a0 = lds_frag(As, wm + lanelo, kb);
      short8 a1 = lds_frag(As, wm + 16 + lanelo, kb);
      short8 b0 = lds_frag(Bs, wn + lanelo, kb);
      short8 b1 = lds_frag(Bs, wn + 16 + lanelo, kb);
      acc[0][0] = mfma16(a0, b0, acc[0][0]);
      acc[0][1] = mfma16(a0, b1, acc[0][1]);
      acc[1][0] = mfma16(a1, b0, acc[1][0]);
      acc[1][1] = mfma16(a1, b1, acc[1][1]);
    }
  }

#pragma unroll
  for (int mi = 0; mi < 2; mi++) {
#pragma unroll
    for (int reg = 0; reg < 4; reg++) {
      const long r = m0 + wm + mi * 16 + quad * 4 + reg;
      long orow = r;
      if (EPI == 2) {
        const long rg = row0 + r;
        int win = (int)(rg / 49);
        int token = (int)(rg - (long)win * 49);
        int bimg = win >> 6, wi = (win & 63) >> 3, wj = win & 7;
        int ti = token / 7, tj = token - ti * 7;
        int h = wi * 7 + ti + 3; if (h >= 56) h -= 56;
        int ww = wj * 7 + tj + 3; if (ww >= 56) ww -= 56;
        orow = (long)bimg * 3136 + h * 56 + ww;
      }
#pragma unroll
      for (int ni = 0; ni < 2; ni++) {
        const int c = n0 + wn + ni * 16 + lanelo;
        float v = acc[mi][ni][reg] + bias[c];
        if (EPI == 0) {
          Cbf[r * Ncols + c] = __float2bfloat16(v);
        } else if (EPI == 1) {
          v = 0.5f * v * (1.f + erff(v * 0.70710678118654752f));
          Cbf[r * Ncols + c] = __float2bfloat16(v);
        } else if (EPI == 2) {
          Cfp[orow * 192 + c] = v + res[orow * 192 + c];
        } else {
          Cfp[r * 192 + c] = v + res[r * 192 + c];
        }
      }
    }
  }
}

// ---------------------------------------------------------------------------
// Fused LN2 + fc1 + GELU + fc2 + residual, in-place on the fp32 tensor.
// One block = 64 rows. Hidden (768) processed in 12 chunks of 64; the fc1
// n-chunk IS the fc2 k-chunk, so only a 64x64 hid tile ever exists (LDS).
// fc2 accumulator (64x192) persists in VGPRs across chunks.
// LDS: As 24K + B1s 24K + B2s 24K + Hs 8K = 80 KB -> 2 blocks/CU.
// ---------------------------------------------------------------------------
__global__ __launch_bounds__(256, 2) void k_mlp(float* xres,
                                                const float* __restrict__ lw,
                                                const float* __restrict__ lb,
                                                const bf16* __restrict__ w1t,
                                                const float* __restrict__ b1,
                                                const bf16* __restrict__ w2t,
                                                const float* __restrict__ b2) {
  __shared__ __align__(16) char As[64 * 384];    // LN'd rows, K=192 (swizzled)
  __shared__ __align__(16) char B1s[64 * 384];   // W1 n-chunk: 64 x 192
  __shared__ __align__(16) char B2s[192 * 128];  // W2 k-chunk: 192 x 64
  __shared__ __align__(16) char Hs[64 * 128];    // gelu(hid) chunk: 64 x 64
  const int t = threadIdx.x, lane = t & 63, wid = t >> 6;
  const int lanelo = lane & 15, quad = lane >> 4;
  const long row0 = (long)blockIdx.x * 64;
  const int wm = (wid >> 1) * 32;        // GEMM1 wave tile 32x32
  const int wn = (wid & 1) * 32;
  const int wn2 = (wid & 1) * 96;        // GEMM2 wave tile 32x96 (same wm)

  // ---- LN2 -> As (bf16, row-XOR swizzled) ----
  for (int i = 0; i < 16; i++) {
    int r = wid * 16 + i;
    const float* src = xres + (row0 + r) * 192;
    float v0 = src[lane], v1 = src[lane + 64], v2 = src[lane + 128];
    float mu = wave_sum(v0 + v1 + v2) * (1.f / 192.f);
    float d0 = v0 - mu, d1 = v1 - mu, d2 = v2 - mu;
    float var = wave_sum(d0 * d0 + d1 * d1 + d2 * d2) * (1.f / 192.f);
    float rs = rsqrtf(var + 1e-5f);
    int sw = (r & 7) << 4;
    *(bf16*)(As + r * 384 + ((2 * lane) ^ sw)) =
        __float2bfloat16(d0 * rs * lw[lane] + lb[lane]);
    *(bf16*)(As + r * 384 + ((128 + 2 * lane) ^ sw)) =
        __float2bfloat16(d1 * rs * lw[lane + 64] + lb[lane + 64]);
    *(bf16*)(As + r * 384 + ((256 + 2 * lane) ^ sw)) =
        __float2bfloat16(d2 * rs * lw[lane + 128] + lb[lane + 128]);
  }

  floatx4 acc2[2][6];
#pragma unroll
  for (int mi = 0; mi < 2; mi++)
#pragma unroll
    for (int ni = 0; ni < 6; ni++) acc2[mi][ni] = (floatx4){0.f, 0.f, 0.f, 0.f};

  for (int nc = 0; nc < 12; nc++) {
    // stage W1 n-chunk (64 rows x 384B) and W2 k-chunk (192 rows x 128B)
#pragma unroll
    for (int i = 0; i < 6; i++) {
      int c = i * 256 + t;
      int r1 = c / 24, j1 = c - r1 * 24;
      gload16((const char*)w1t + (long)(nc * 64 + r1) * 384 +
                  ((j1 * 16) ^ ((r1 & 7) << 4)),
              B1s + c * 16);
      int r2 = c >> 3, j2 = c & 7;
      gload16((const char*)w2t + (long)r2 * 1536 + nc * 128 +
                  ((j2 * 16) ^ ((r2 & 7) << 4)),
              B2s + c * 16);
    }
    __syncthreads();  // stage drained; (iter 0: also As ready)

    // GEMM1: hid chunk 64x64 (K=192), wave tile 32x32
    floatx4 acc1[2][2];
#pragma unroll
    for (int mi = 0; mi < 2; mi++)
#pragma unroll
      for (int ni = 0; ni < 2; ni++) acc1[mi][ni] = (floatx4){0.f, 0.f, 0.f, 0.f};
#pragma unroll
    for (int kk = 0; kk < 6; kk++) {
      const int kb = kk * 64 + quad * 16;
      short8 a0 = lds_frag(As, wm + lanelo, kb);
      short8 a1 = lds_frag(As, wm + 16 + lanelo, kb);
      short8 b0 = lds_frag(B1s, wn + lanelo, kb);
      short8 b1f = lds_frag(B1s, wn + 16 + lanelo, kb);
      acc1[0][0] = mfma16(a0, b0, acc1[0][0]);
      acc1[0][1] = mfma16(a0, b1f, acc1[0][1]);
      acc1[1][0] = mfma16(a1, b0, acc1[1][0]);
      acc1[1][1] = mfma16(a1, b1f, acc1[1][1]);
    }

    // bias + exact GELU -> Hs (bf16, swizzled)
#pragma unroll
    for (int ni = 0; ni < 2; ni++) {
      const int cl = wn + ni * 16 + lanelo;
      const float b1v = b1[nc * 64 + cl];
#pragma unroll
      for (int mi = 0; mi < 2; mi++)
#pragma unroll
        for (int reg = 0; reg < 4; reg++) {
          int r = wm + mi * 16 + quad * 4 + reg;
          float v = acc1[mi][ni][reg] + b1v;
          v = 0.5f * v * (1.f + erff(v * 0.70710678118654752f));
          *(bf16*)(Hs + r * 128 + ((2 * cl) ^ ((r & 7) << 4))) =
              __float2bfloat16(v);
        }
    }
    __syncthreads();  // hid chunk ready

    // GEMM2 partial: out 64x192 += Hs(64x64) * W2chunk^T, wave tile 32x96
#pragma unroll
    for (int ks = 0; ks < 2; ks++) {
      const int kb = ks * 64 + quad * 16;
      short8 ha0 = lds_frag128(Hs, wm + lanelo, kb);
      short8 ha1 = lds_frag128(Hs, wm + 16 + lanelo, kb);
#pragma unroll
      for (int ni = 0; ni < 6; ni++) {
        short8 bv = lds_frag128(B2s, wn2 + ni * 16 + lanelo, kb);
        acc2[0][ni] = mfma16(ha0, bv, acc2[0][ni]);
        acc2[1][ni] = mfma16(ha1, bv, acc2[1][ni]);
      }
    }
    __syncthreads();  // chunk consumed; safe to overwrite B1s/B2s/Hs
  }

  // epilogue: + bias2 + residual, fp32 in-place
#pragma unroll
  for (int mi = 0; mi < 2; mi++)
#pragma unroll
    for (int ni = 0; ni < 6; ni++) {
      const int c = wn2 + ni * 16 + lanelo;
      const float b2v = b2[c];
#pragma unroll
      for (int reg = 0; reg < 4; reg++) {
        const long g = (row0 + wm + mi * 16 + quad * 4 + reg) * 192 + c;
        xres[g] = acc2[mi][ni][reg] + b2v + xres[g];
      }
    }
}

// ---------------------------------------------------------------------------
// Windowed attention over a CHUNK of windows. One wave per (window, head).
// N=49 padded to 64. qkv rows are chunk-local; `out` is pre-offset.
// Spatial labels use win & 63 (valid: chunks are whole images).
// ---------------------------------------------------------------------------
__global__ __launch_bounds__(256, 2) void k_attn(const bf16* __restrict__ qkv,
                                                 const float* __restrict__ rpb,
                                                 bf16* __restrict__ out) {
  __shared__ __align__(16) bf16 smem[4 * 7424];
  const int t = threadIdx.x, lane = t & 63, wid = t >> 6;
  const int lanelo = lane & 15, quad = lane >> 4;
  const int unit = blockIdx.x * 4 + wid;
  const int win = unit / 6, head = unit - win * 6;
  bf16* Qs = smem + wid * 7424;  // 64 rows, stride 40
  bf16* Ks = Qs + 2560;          // 64 rows, stride 40
  bf16* Vt = Qs + 5120;          // 32 rows (d), stride 72, cols = token
  bf16* Ps = Qs;                 // 64 rows, stride 72 (4608 <= 5120, reuse Q/K)
  const long rowbase = (long)win * 49;
  const bf16* base = qkv + rowbase * 576 + head * 32;

  // stage Q, K (row-major) and V transposed; 49 rows x 32 cols each
  for (int idx = lane; idx < 196; idx += 64) {
    int tok = idx >> 2, ch = (idx & 3) * 8;
    *(uint4*)(&Qs[tok * 40 + ch]) = *(const uint4*)(base + (long)tok * 576 + ch);
    *(uint4*)(&Ks[tok * 40 + ch]) = *(const uint4*)(base + (long)tok * 576 + 192 + ch);
    union { uint4 u; bf16 h[8]; } tv;
    tv.u = *(const uint4*)(base + (long)tok * 576 + 384 + ch);
#pragma unroll
    for (int jj = 0; jj < 8; jj++) Vt[(ch + jj) * 72 + tok] = tv.h[jj];
  }
  // zero V pad tokens 49..63 (keep P*V clean in pad region)
  for (int idx = lane; idx < 480; idx += 64) {
    int d = idx / 15, c = 49 + (idx - d * 15);
    Vt[d * 72 + c] = __float2bfloat16(0.f);
  }
  __syncthreads();

  // S = Q * K^T : 64x64 via 4x4 fragments, single K-step (HD=32)
  floatx4 aS[4][4];
#pragma unroll
  for (int mi = 0; mi < 4; mi++)
#pragma unroll
    for (int ni = 0; ni < 4; ni++) aS[mi][ni] = (floatx4){0.f, 0.f, 0.f, 0.f};
  {
    short8 aq[4], bk[4];
#pragma unroll
    for (int mi = 0; mi < 4; mi++)
      aq[mi] = *(const short8*)(&Qs[(mi * 16 + lanelo) * 40 + quad * 8]);
#pragma unroll
    for (int ni = 0; ni < 4; ni++)
      bk[ni] = *(const short8*)(&Ks[(ni * 16 + lanelo) * 40 + quad * 8]);
#pragma unroll
    for (int mi = 0; mi < 4; mi++)
#pragma unroll
      for (int ni = 0; ni < 4; ni++) aS[mi][ni] = mfma16(aq[mi], bk[ni], aS[mi][ni]);
  }

  // per-column (key j) tables for this lane
  const int w_in = win & 63, wiw = w_in >> 3, wjw = w_in & 7;
  int cTi[4], cTj[4], cLab[4];
  bool cval[4];
#pragma unroll
  for (int ni = 0; ni < 4; ni++) {
    int j = ni * 16 + lanelo;
    cval[ni] = (j < 49);
    if (j > 48) j = 48;
    int ti = j / 7, tj = j - ti * 7;
    int rr = wiw * 7 + ti, cc = wjw * 7 + tj;
    cTi[ni] = ti;
    cTj[ni] = tj;
    cLab[ni] = ((rr < 49) ? 0 : (rr < 53 ? 1 : 2)) * 3 +
               ((cc < 49) ? 0 : (cc < 53 ? 1 : 2));
  }

  const float scale = 0.17677669529663687f;  // 1/sqrt(32)
  float rinv[16];
#pragma unroll
  for (int mi = 0; mi < 4; mi++) {
#pragma unroll
    for (int reg = 0; reg < 4; reg++) {
      int i = mi * 16 + quad * 4 + reg;
      if (i > 48) i = 48;
      int ti = i / 7, tj = i - ti * 7;
      int rr = wiw * 7 + ti, cc = wjw * 7 + tj;
      int rlab = ((rr < 49) ? 0 : (rr < 53 ? 1 : 2)) * 3 +
                 ((cc < 49) ? 0 : (cc < 53 ? 1 : 2));
      float sv[4];
      float mx = -1e30f;
#pragma unroll
      for (int ni = 0; ni < 4; ni++) {
        float s;
        if (cval[ni]) {
          int ridx = (ti - cTi[ni] + 6) * 13 + (tj - cTj[ni] + 6);
          float bb = rpb[ridx * 6 + head];
          if (rlab != cLab[ni]) bb -= 100.f;
          s = aS[mi][ni][reg] * scale + bb;
        } else {
          s = -1e30f;
        }
        sv[ni] = s;
        mx = fmaxf(mx, s);
      }
      mx = fmaxf(mx, __shfl_xor(mx, 1));
      mx = fmaxf(mx, __shfl_xor(mx, 2));
      mx = fmaxf(mx, __shfl_xor(mx, 4));
      mx = fmaxf(mx, __shfl_xor(mx, 8));
      float sum = 0.f;
#pragma unroll
      for (int ni = 0; ni < 4; ni++) {
        float p = __expf(sv[ni] - mx);
        sv[ni] = p;
        sum += p;
      }
      sum += __shfl_xor(sum, 1);
      sum += __shfl_xor(sum, 2);
      sum += __shfl_xor(sum, 4);
      sum += __shfl_xor(sum, 8);
      rinv[mi * 4 + reg] = 1.f / sum;
#pragma unroll
      for (int ni = 0; ni < 4; ni++) aS[mi][ni][reg] = sv[ni];
    }
  }
  __syncthreads();

  // P -> LDS in A-operand layout (row i, contiguous j)
#pragma unroll
  for (int mi = 0; mi < 4; mi++)
#pragma unroll
    for (int ni = 0; ni < 4; ni++)
#pragma unroll
      for (int reg = 0; reg < 4; reg++) {
        int i = mi * 16 + quad * 4 + reg, j = ni * 16 + lanelo;
        Ps[i * 72 + j] = __float2bfloat16(aS[mi][ni][reg]);
      }
  __syncthreads();

  // O = P * V : 64x32, K=64 in 2 steps
  floatx4 aO[4][2];
#pragma unroll
  for (int mi = 0; mi < 4; mi++)
#pragma unroll
    for (int ni = 0; ni < 2; ni++) aO[mi][ni] = (floatx4){0.f, 0.f, 0.f, 0.f};
#pragma unroll
  for (int k0 = 0; k0 < 64; k0 += 32) {
    short8 ap[4], bv[2];
#pragma unroll
    for (int mi = 0; mi < 4; mi++)
      ap[mi] = *(const short8*)(&Ps[(mi * 16 + lanelo) * 72 + k0 + quad * 8]);
#pragma unroll
    for (int ni = 0; ni < 2; ni++)
      bv[ni] = *(const short8*)(&Vt[(ni * 16 + lanelo) * 72 + k0 + quad * 8]);
#pragma unroll
    for (int mi = 0; mi < 4; mi++)
#pragma unroll
      for (int ni = 0; ni < 2; ni++) aO[mi][ni] = mfma16(ap[mi], bv[ni], aO[mi][ni]);
  }

#pragma unroll
  for (int mi = 0; mi < 4; mi++)
#pragma unroll
    for (int reg = 0; reg < 4; reg++) {
      int i = mi * 16 + quad * 4 + reg;
      if (i < 49) {
        float rv = rinv[mi * 4 + reg];
#pragma unroll
        for (int ni = 0; ni < 2; ni++) {
          int d = ni * 16 + lanelo;
          out[(rowbase + i) * 192 + head * 32 + d] =
              __float2bfloat16(aO[mi][ni][reg] * rv);
        }
      }
    }
}

// ---------------------------------------------------------------------------
extern "C" void kernel_launch(void* const* d_in, const int* in_sizes, int n_in,
                              void* d_out, int out_size, void* d_ws, size_t ws_size,
                              hipStream_t stream) {
  const float* x     = (const float*)d_in[0];
  const float* n1w   = (const float*)d_in[1];
  const float* n1b   = (const float*)d_in[2];
  const float* qkvw  = (const float*)d_in[3];
  const float* qkvb  = (const float*)d_in[4];
  const float* rpb   = (const float*)d_in[5];
  const float* projw = (const float*)d_in[6];
  const float* projb = (const float*)d_in[7];
  const float* n2w   = (const float*)d_in[8];
  const float* n2b   = (const float*)d_in[9];
  const float* fc1w  = (const float*)d_in[10];
  const float* fc1b  = (const float*)d_in[11];
  const float* fc2w  = (const float*)d_in[12];
  const float* fc2b  = (const float*)d_in[13];
  float* outf = (float*)d_out;  // residual buffer x2, then final output

  // Chunking (attention phase): 4 chunks x 1024 windows = 50176 rows each.
  const long CR = 50176;
  const int  NCH = 4;

  // workspace layout:
  //   B0 [0,        77070336)  xw bf16 (200704x192)
  //   B1 [77070336, 134873088) qkv chunk bf16 (50176x576)
  //   B2 [134873088,154140672) attn chunk bf16 (50176x192)
  //   W  [154140672, ...)      bf16 weights (~0.9 MB)
  char* ws = (char*)d_ws;
  bf16* xw      = (bf16*)(ws + 0);
  bf16* qkvC    = (bf16*)(ws + 77070336LL);
  bf16* attC    = (bf16*)(ws + 134873088LL);
  bf16* wt_qkv  = (bf16*)(ws + 154140672LL);                  // 576x192
  bf16* wt_proj = (bf16*)(ws + 154140672LL + 221184LL);       // 192x192
  bf16* wt_fc1  = (bf16*)(ws + 154140672LL + 294912LL);       // 768x192
  bf16* wt_fc2  = (bf16*)(ws + 154140672LL + 589824LL);       // 192x768

  // transpose + cast weights to bf16 (N x K)
  k_wt<<<dim3((192 * 576 + 255) / 256), 256, 0, stream>>>(qkvw, wt_qkv, 192, 576);
  k_wt<<<dim3((192 * 192 + 255) / 256), 256, 0, stream>>>(projw, wt_proj, 192, 192);
  k_wt<<<dim3((192 * 768 + 255) / 256), 256, 0, stream>>>(fc1w, wt_fc1, 192, 768);
  k_wt<<<dim3((768 * 192 + 255) / 256), 256, 0, stream>>>(fc2w, wt_fc2, 768, 192);

  // LN1 + shift + window partition -> xw (window-order rows, full tensor)
  k_ln<true><<<dim3(50176), 256, 0, stream>>>(x, n1w, n1b, xw);

  // attention phase, chunked
  for (int c = 0; c < NCH; c++) {
    const long r0 = c * CR;
    k_gemm<0><<<dim3(784, 9), 256, 0, stream>>>(xw + r0 * 192, wt_qkv, qkvb,
                                                qkvC, nullptr, nullptr, 576, 192, 0);
    k_attn<<<dim3(1536), 256, 0, stream>>>(qkvC, rpb, attC);
    k_gemm<2><<<dim3(784, 3), 256, 0, stream>>>(attC, wt_proj, projb, nullptr,
                                                outf, x, 192, 192, r0);
  }

  // fused LN2 + MLP + residual, in-place on d_out (64 rows per block)
  k_mlp<<<dim3(3136), 256, 0, stream>>>(outf, n2w, n2b, wt_fc1, fc1b,
                                        wt_fc2, fc2b);
}